// Round 10
// baseline (232.312 us; speedup 1.0000x reference)
//
#include <hip/hip_runtime.h>
#include <math.h>

#define B_ 64
#define T_ 256
#define K_ 128
#define S_ 8      // segments
#define SL_ 32    // segment length

typedef const __attribute__((address_space(1))) void* gas1_t;
typedef __attribute__((address_space(3))) void* las3_t;
typedef float f32x4 __attribute__((ext_vector_type(4)));
typedef int   i32x8 __attribute__((ext_vector_type(8)));
typedef short bf16x8 __attribute__((ext_vector_type(8)));

static __device__ __forceinline__ unsigned int bf16rne(float x) {
    unsigned int u = __builtin_bit_cast(unsigned int, x);
    return (u + 0x7FFFu + ((u >> 16) & 1u)) >> 16;
}
static __device__ __forceinline__ unsigned int pkbf16(float a, float b) {
    return bf16rne(a) | (bf16rne(b) << 16);
}
static __device__ __forceinline__ float bf8_to_f32(unsigned int byte) {
    // e5m2 == truncated fp16: byte<<8 are fp16 bits
    unsigned short h = (unsigned short)(byte << 8);
    return (float)__builtin_bit_cast(_Float16, h);
}

// ---------------- Phase 1: segment products ------------------------------
// Block (b,s) = 512 thr = 8 waves. Wave wv evolves columns [16wv,16wv+16) of
// P_s = prod_{t in seg, t<L} diag(exp(y_t)) * E  as 16 INDEPENDENT register-
// closed matvec recurrences (R8's sigma trick; N-dim now carries 16 distinct
// columns, same 8 MFMA/step). Per-column renorm each step (lane ci = column).
// 4 waves/SIMD hide the dependency latency that capped R6/R8.
__global__ __launch_bounds__(512, 4) void crf_seg_kernel(
    const float* __restrict__ y,
    const float* __restrict__ mask,
    const float* __restrict__ trans,
    unsigned short* __restrict__ matsWS,   // (B*S, 128,128) col-major bf16
    float* __restrict__ scalesWS)          // (B*S, 128) per-column log scales
{
    const int bc  = blockIdx.x;            // b*S_ + s
    const int b   = bc >> 3;
    const int sg  = bc & 7;
    const int tid = threadIdx.x;
    const int wv  = tid >> 6;              // 0..7 : column tile
    const int lane = tid & 63;
    const int g   = lane >> 4;             // k-block / row-block selector
    const int ci  = lane & 15;             // column within tile (and A-row sel)

    __shared__ __align__(16) float bufA[4352];       // 17.4KB: raw y / export stage
    __shared__ __align__(16) float bufB[SL_ * 144];  // 18.4KB: swizzled exp(y)
    __shared__ int lenS[4];

    // ---- DMA y segment (16KB) ----
    const float* gy = y + ((size_t)b * T_ + sg * SL_) * K_;
    #pragma unroll
    for (int q = 0; q < 2; ++q) {
        const int seg = 2 * wv + q;
        __builtin_amdgcn_global_load_lds((gas1_t)(gy + seg * 256 + lane * 4),
                                         (las3_t)(bufA + seg * 256), 16, 0, 0);
    }

    // ---- sequence length (mask contiguous 1.0/0.0), waves 0..3 ----
    if (wv < 4) {
        float mval = mask[b * T_ + tid];
        unsigned long long bal = __ballot(mval != 0.0f);
        if (lane == 0) lenS[wv] = __popcll(bal);
    }

    // ---- A-frags: E=exp(trans) e4m3, rows sigma(rt,ci)=32(ci>>2)+4rt+(ci&3) ----
    i32x8 A[8];
    #pragma unroll
    for (int rt = 0; rt < 8; ++rt) {
        const int R = 32 * (ci >> 2) + 4 * rt + (ci & 3);
        const float* tp = trans + R * K_ + 32 * g;
        i32x8 a;
        #pragma unroll
        for (int dw = 0; dw < 8; ++dw) {
            f32x4 v4 = *(const f32x4*)(tp + 4 * dw);
            int d = 0;
            d = __builtin_amdgcn_cvt_pk_fp8_f32(__expf(v4.x), __expf(v4.y), d, false);
            d = __builtin_amdgcn_cvt_pk_fp8_f32(__expf(v4.z), __expf(v4.w), d, true);
            a[dw] = d;
        }
        A[rt] = a;
    }

    // ---- init B = identity column col0 = 16wv+ci (e5m2 1.0 = 0x3C) ----
    const int col0 = 16 * wv + ci;
    i32x8 Bv = (i32x8){0, 0, 0, 0, 0, 0, 0, 0};
    if (g == (wv >> 1)) {
        const int j = 16 * (wv & 1) + ci;        // k - 32g, in [0,32)
        Bv[j >> 2] = 0x3C << (8 * (j & 3));
    }
    float rDiv = 1.0f, c_acc = 0.0f;

    asm volatile("s_waitcnt vmcnt(0)" ::: "memory");
    __syncthreads();

    // ---- pre-exp into swizzled bufB: row 32g'+rr at t*144 + 36g' + rr ----
    {
        const int e0 = tid * 8;
        const int t0 = e0 >> 7, r0 = e0 & 127;
        const int gg = r0 >> 5, rr = r0 & 31;
        f32x4 a = *(const f32x4*)(bufA + e0);
        f32x4 b2 = *(const f32x4*)(bufA + e0 + 4);
        a.x = __expf(a.x); a.y = __expf(a.y); a.z = __expf(a.z); a.w = __expf(a.w);
        b2.x = __expf(b2.x); b2.y = __expf(b2.y); b2.z = __expf(b2.z); b2.w = __expf(b2.w);
        *(f32x4*)(bufB + t0 * 144 + gg * 36 + rr)     = a;
        *(f32x4*)(bufB + t0 * 144 + gg * 36 + rr + 4) = b2;
    }
    __syncthreads();
    const int L = lenS[0] + lenS[1] + lenS[2] + lenS[3];   // in [128,256]
    int ns = L - sg * SL_;
    ns = ns < 0 ? 0 : (ns > SL_ ? SL_ : ns);

    // ---- barrier-free scan: 8 MFMA/step, register-closed per column ----
    for (int tt = 0; tt < ns; ++tt) {
        const float* ey = bufB + tt * 144 + 36 * g;
        f32x4 sv = {0.f, 0.f, 0.f, 0.f};
        i32x8 Bn;
        #pragma unroll
        for (int rt = 0; rt < 8; ++rt) {
            f32x4 u = __builtin_amdgcn_mfma_scale_f32_16x16x128_f8f6f4(
                A[rt], Bv, (f32x4){0.f, 0.f, 0.f, 0.f},
                0 /*A fmt e4m3*/, 1 /*B fmt e5m2*/, 0, 127, 0, 127);
            f32x4 e4 = *(const f32x4*)(ey + 4 * rt);   // rows 32g+4rt..+3
            f32x4 ww = u * e4 * rDiv;
            sv += ww;
            int d = 0;
            d = __builtin_amdgcn_cvt_pk_bf8_f32(ww.x, ww.y, d, false);
            d = __builtin_amdgcn_cvt_pk_bf8_f32(ww.z, ww.w, d, true);
            Bn[rt] = d;
        }
        // per-COLUMN sum: lane's 32 rows + combine over g (xor16, xor32)
        float S = (sv.x + sv.y) + (sv.z + sv.w);
        S += __shfl_xor(S, 16);
        S += __shfl_xor(S, 32);
        c_acc += __logf(S);
        rDiv = __builtin_amdgcn_rcpf(S);
        Bv = Bn;
    }

    // ---- per-column log scale ----
    if (g == 0) scalesWS[bc * K_ + col0] = c_acc;

    // ---- export stored P (= decode(Bv) * rDiv) col-major bf16, 2 passes ----
    unsigned short* stage = (unsigned short*)bufA;   // 64 cols x 136 pitch
    unsigned short* gm = matsWS + (size_t)bc * (K_ * K_);
    #pragma unroll
    for (int p = 0; p < 2; ++p) {
        __syncthreads();
        if ((wv >> 2) == p) {
            const int cl = 16 * (wv & 3) + ci;       // local column
            #pragma unroll
            for (int rt = 0; rt < 8; ++rt) {
                const unsigned int dwv = (unsigned int)Bv[rt];
                float f0 = bf8_to_f32(dwv & 255u)         * rDiv;
                float f1 = bf8_to_f32((dwv >> 8) & 255u)  * rDiv;
                float f2 = bf8_to_f32((dwv >> 16) & 255u) * rDiv;
                float f3 = bf8_to_f32((dwv >> 24) & 255u) * rDiv;
                uint2 d = make_uint2(pkbf16(f0, f1), pkbf16(f2, f3));
                *(uint2*)&stage[cl * 136 + 32 * g + 4 * rt] = d;   // rows 32g+4rt..+3
            }
        }
        __syncthreads();
        const int cc = tid >> 3, rq = tid & 7;       // 64 cols x 8 row-chunks
        const unsigned short* sp = stage + cc * 136 + 16 * rq;
        bf16x8 v0 = *(const bf16x8*)sp;
        bf16x8 v1 = *(const bf16x8*)(sp + 8);
        unsigned short* gp = gm + (size_t)(64 * p + cc) * K_ + 16 * rq;
        *(bf16x8*)gp = v0;
        *(bf16x8*)(gp + 8) = v1;
    }
}

// ---------------- Phase 2: combine (64 blocks x 256 thr) -----------------
// v <- P_s * exp(sc + ln v - m) per segment, fp32, col-major P reads.
__global__ __launch_bounds__(256) void crf_combine_kernel(
    const unsigned short* __restrict__ mats,
    const float* __restrict__ scales,
    float* __restrict__ out)
{
    const int b = blockIdx.x, tid = threadIdx.x;
    const int lane = tid & 63;

    __shared__ float vS[K_], tS[K_], aS[K_], puS[2][K_];

    if (tid < K_) vS[tid] = (tid == 2) ? 1.0f : 0.0f;   // one-hot SOS
    float c = 0.0f;

    for (int sg = 0; sg < S_; ++sg) {
        __syncthreads();
        const float* sc = scales + ((size_t)b * S_ + sg) * K_;
        if (tid < K_) tS[tid] = sc[tid] + __logf(vS[tid]);
        __syncthreads();
        // redundant per-wave max over tS[0..127]
        float m = fmaxf(tS[lane], tS[lane + 64]);
        m = fmaxf(m, __shfl_xor(m, 1));
        m = fmaxf(m, __shfl_xor(m, 2));
        m = fmaxf(m, __shfl_xor(m, 4));
        m = fmaxf(m, __shfl_xor(m, 8));
        m = fmaxf(m, __shfl_xor(m, 16));
        m = fmaxf(m, __shfl_xor(m, 32));
        if (tid < K_) aS[tid] = __expf(tS[tid] - m);
        __syncthreads();

        const unsigned short* P = mats + ((size_t)b * S_ + sg) * (K_ * K_);
        const int h = tid >> 7, i = tid & 127;
        float acc = 0.0f;
        #pragma unroll
        for (int j0 = 0; j0 < 64; ++j0) {
            const int j = 64 * h + j0;
            unsigned int uv = P[(size_t)j * K_ + i];          // coalesced
            float pv = __builtin_bit_cast(float, uv << 16);   // bf16 -> f32
            acc = fmaf(aS[j], pv, acc);
        }
        puS[h][i] = acc;
        __syncthreads();
        if (tid < K_) tS[tid] = puS[0][tid] + puS[1][tid];    // u_i
        __syncthreads();
        float Ssum = tS[lane] + tS[lane + 64];
        Ssum += __shfl_xor(Ssum, 1);
        Ssum += __shfl_xor(Ssum, 2);
        Ssum += __shfl_xor(Ssum, 4);
        Ssum += __shfl_xor(Ssum, 8);
        Ssum += __shfl_xor(Ssum, 16);
        Ssum += __shfl_xor(Ssum, 32);
        if (tid < K_) vS[tid] = tS[tid] * __builtin_amdgcn_rcpf(Ssum);
        c += m + __logf(Ssum);
    }
    if (tid == 0) out[b] = c;    // v normalized to sum 1 each segment
}

extern "C" void kernel_launch(void* const* d_in, const int* in_sizes, int n_in,
                              void* d_out, int out_size, void* d_ws, size_t ws_size,
                              hipStream_t stream) {
    const float* y     = (const float*)d_in[0];   // (B, T, K) fp32
    const float* mask  = (const float*)d_in[1];   // (B, T)    fp32 0/1
    const float* trans = (const float*)d_in[2];   // (K, K)    fp32
    float* out = (float*)d_out;                    // (B,)      fp32

    unsigned short* mats = (unsigned short*)d_ws;  // 512*128*128 bf16 = 16 MiB
    float* scales = (float*)((char*)d_ws + (size_t)B_ * S_ * K_ * K_ * 2);

    crf_seg_kernel<<<B_ * S_, 512, 0, stream>>>(y, mask, trans, mats, scales);
    crf_combine_kernel<<<B_, 256, 0, stream>>>(mats, scales, out);
}

// Round 11
// 167.549 us; speedup vs baseline: 1.3865x; 1.3865x over previous
//
#include <hip/hip_runtime.h>
#include <math.h>

#define B_ 64
#define T_ 256
#define K_ 128
#define S_ 8      // segments
#define SL_ 32    // segment length

typedef const __attribute__((address_space(1))) void* gas1_t;
typedef __attribute__((address_space(3))) void* las3_t;
typedef float f32x4 __attribute__((ext_vector_type(4)));
typedef int   i32x4 __attribute__((ext_vector_type(4)));
typedef int   i32x8 __attribute__((ext_vector_type(8)));
typedef short bf16x8 __attribute__((ext_vector_type(8)));

static __device__ __forceinline__ unsigned int bf16rne(float x) {
    unsigned int u = __builtin_bit_cast(unsigned int, x);
    return (u + 0x7FFFu + ((u >> 16) & 1u)) >> 16;
}
static __device__ __forceinline__ unsigned int pkbf16(float a, float b) {
    return bf16rne(a) | (bf16rne(b) << 16);
}
static __device__ __forceinline__ float bf8_to_f32(unsigned int byte) {
    // e5m2 == truncated fp16: byte<<8 are fp16 bits
    unsigned short h = (unsigned short)(byte << 8);
    return (float)__builtin_bit_cast(_Float16, h);
}
static __device__ __forceinline__ float hi_bf16(int d) {
    return __builtin_bit_cast(float, d & 0xFFFF0000);
}
static __device__ __forceinline__ float lo_bf16(int d) {
    return __builtin_bit_cast(float, d << 16);
}

// ---------------- Phase 1: segment products ------------------------------
// Block (b,s) = 512 thr = 8 waves; wave wv evolves columns [16wv,16wv+16) of
// P_s = prod_t diag(exp(y_t))*E as 16 independent register-closed matvec
// recurrences (sigma-permuted A rows; 8 x mfma_scale 16x16x128 per step).
// Renormalization by powers of two via the per-lane e8m0 scaleB operand of
// the NEXT step's MFMA (exact integer bookkeeping, zero VALU rescale).
// launch_bounds(512,2): cap 256 VGPR -> A[8] (64 regs) stays in registers
// (R9's (512,4) cap caused catastrophic scratch spill: VGPR=64, 247MB writes).
__global__ __launch_bounds__(512, 2) void crf_seg_kernel(
    const float* __restrict__ y,
    const float* __restrict__ mask,
    const float* __restrict__ trans,
    unsigned short* __restrict__ matsWS,   // (B*S, 128,128) col-major bf16
    float* __restrict__ scalesWS)          // (B*S, 128) per-column log scales
{
    const int bc  = blockIdx.x;            // b*S_ + s
    const int b   = bc >> 3;
    const int sg  = bc & 7;
    const int tid = threadIdx.x;
    const int wv  = tid >> 6;              // 0..7 : column tile
    const int lane = tid & 63;
    const int g   = lane >> 4;             // k-block / row-block selector
    const int ci  = lane & 15;             // column within tile (and A-row sel)

    __shared__ __align__(16) float bufA[4352];              // 17.4KB raw y / export stage
    __shared__ __align__(16) unsigned short bufB16[SL_ * 136]; // 8.7KB bf16 exp(y)
    __shared__ int lenS[4];

    // ---- DMA y segment (16KB) ----
    const float* gy = y + ((size_t)b * T_ + sg * SL_) * K_;
    #pragma unroll
    for (int q = 0; q < 2; ++q) {
        const int seg = 2 * wv + q;
        __builtin_amdgcn_global_load_lds((gas1_t)(gy + seg * 256 + lane * 4),
                                         (las3_t)(bufA + seg * 256), 16, 0, 0);
    }

    // ---- sequence length (mask contiguous 1.0/0.0), waves 0..3 ----
    if (wv < 4) {
        float mval = mask[b * T_ + tid];
        unsigned long long bal = __ballot(mval != 0.0f);
        if (lane == 0) lenS[wv] = __popcll(bal);
    }

    // ---- A-frags: E=exp(trans) e4m3, rows sigma(rt,ci)=32(ci>>2)+4rt+(ci&3) ----
    i32x8 A[8];
    #pragma unroll
    for (int rt = 0; rt < 8; ++rt) {
        const int R = 32 * (ci >> 2) + 4 * rt + (ci & 3);
        const float* tp = trans + R * K_ + 32 * g;
        i32x8 a;
        #pragma unroll
        for (int dw = 0; dw < 8; ++dw) {
            f32x4 v4 = *(const f32x4*)(tp + 4 * dw);
            int d = 0;
            d = __builtin_amdgcn_cvt_pk_fp8_f32(__expf(v4.x), __expf(v4.y), d, false);
            d = __builtin_amdgcn_cvt_pk_fp8_f32(__expf(v4.z), __expf(v4.w), d, true);
            a[dw] = d;
        }
        A[rt] = a;
    }

    // ---- init B = identity column col0 = 16wv+ci (e5m2 1.0 = 0x3C) ----
    const int col0 = 16 * wv + ci;
    i32x8 Bv = (i32x8){0, 0, 0, 0, 0, 0, 0, 0};
    if (g == (wv >> 1)) {
        const int j = 16 * (wv & 1) + ci;        // k - 32g, in [0,32)
        Bv[j >> 2] = 0x3C << (8 * (j & 3));
    }

    asm volatile("s_waitcnt vmcnt(0)" ::: "memory");
    __syncthreads();

    // ---- pre-exp into bf16 LDS: [t][row], pitch 136 shorts ----
    {
        const int e0 = tid * 8;
        const int t0 = e0 >> 7, r0 = e0 & 127;
        f32x4 a = *(const f32x4*)(bufA + e0);
        f32x4 b2 = *(const f32x4*)(bufA + e0 + 4);
        uint4 u = make_uint4(pkbf16(__expf(a.x), __expf(a.y)),
                             pkbf16(__expf(a.z), __expf(a.w)),
                             pkbf16(__expf(b2.x), __expf(b2.y)),
                             pkbf16(__expf(b2.z), __expf(b2.w)));
        *(uint4*)(bufB16 + t0 * 136 + r0) = u;
    }
    __syncthreads();
    const int L = lenS[0] + lenS[1] + lenS[2] + lenS[3];   // in [128,256]
    int ns = L - sg * SL_;
    ns = ns < 0 ? 0 : (ns > SL_ ? SL_ : ns);

    int Nacc = 0;        // sum of applied power-2 exponents (per column)
    int n_pend = 0;      // exponent to apply at next step

    // ---- barrier-free scan: 8 MFMA/step, register-closed per column ----
    for (int tt = 0; tt < ns; ++tt) {
        int bby = 127 - n_pend;
        bby = bby < 1 ? 1 : (bby > 254 ? 254 : bby);
        const int bscale = bby * 0x01010101;     // replicate e8m0 byte
        Nacc += n_pend;

        const unsigned short* eyp = bufB16 + tt * 136 + 32 * g;
        i32x4 eh0 = *(const i32x4*)(eyp);
        i32x4 eh1 = *(const i32x4*)(eyp + 8);
        i32x4 eh2 = *(const i32x4*)(eyp + 16);
        i32x4 eh3 = *(const i32x4*)(eyp + 24);
        int ed[8] = {eh0[0], eh0[1], eh0[2], eh0[3], eh1[0], eh1[1], eh1[2], eh1[3]};
        int ed2[8] = {eh2[0], eh2[1], eh2[2], eh2[3], eh3[0], eh3[1], eh3[2], eh3[3]};

        f32x4 sv = {0.f, 0.f, 0.f, 0.f};
        i32x8 Bn;
        #pragma unroll
        for (int rt = 0; rt < 8; ++rt) {
            f32x4 u = __builtin_amdgcn_mfma_scale_f32_16x16x128_f8f6f4(
                A[rt], Bv, (f32x4){0.f, 0.f, 0.f, 0.f},
                0 /*A fmt e4m3*/, 1 /*B fmt e5m2*/,
                0, 0x7F7F7F7F /*scaleA = 1.0*/, 0, bscale /*scaleB = 2^-n*/);
            const int d0 = (rt < 4) ? ed[2 * rt] : ed2[2 * (rt - 4)];
            const int d1 = (rt < 4) ? ed[2 * rt + 1] : ed2[2 * (rt - 4) + 1];
            f32x4 e4 = {lo_bf16(d0), hi_bf16(d0), lo_bf16(d1), hi_bf16(d1)};
            f32x4 ww = u * e4;                   // rows 32g+4rt..+3
            sv += ww;
            int d = 0;
            d = __builtin_amdgcn_cvt_pk_bf8_f32(ww.x, ww.y, d, false);
            d = __builtin_amdgcn_cvt_pk_bf8_f32(ww.z, ww.w, d, true);
            Bn[rt] = d;
        }
        // per-COLUMN sum S -> next power-2 exponent
        float S = (sv.x + sv.y) + (sv.z + sv.w);
        S += __shfl_xor(S, 16);
        S += __shfl_xor(S, 32);
        n_pend = ((__builtin_bit_cast(int, S) >> 23) & 255) - 126;  // S*2^-n in [0.5,1)
        Bv = Bn;
    }

    // ---- per-column log scale: true col = stored * 2^{+Nacc} ----
    if (g == 0) scalesWS[bc * K_ + col0] = (float)Nacc * 0.69314718f;

    // ---- export stored P (decode Bv) col-major bf16, 2 passes ----
    unsigned short* stage = (unsigned short*)bufA;   // 64 cols x 136 pitch
    unsigned short* gm = matsWS + (size_t)bc * (K_ * K_);
    #pragma unroll
    for (int p = 0; p < 2; ++p) {
        __syncthreads();
        if ((wv >> 2) == p) {
            const int cl = 16 * (wv & 3) + ci;       // local column
            #pragma unroll
            for (int rt = 0; rt < 8; ++rt) {
                const unsigned int dwv = (unsigned int)Bv[rt];
                float f0 = bf8_to_f32(dwv & 255u);
                float f1 = bf8_to_f32((dwv >> 8) & 255u);
                float f2 = bf8_to_f32((dwv >> 16) & 255u);
                float f3 = bf8_to_f32((dwv >> 24) & 255u);
                uint2 d = make_uint2(pkbf16(f0, f1), pkbf16(f2, f3));
                *(uint2*)&stage[cl * 136 + 32 * g + 4 * rt] = d;   // rows 32g+4rt..+3
            }
        }
        __syncthreads();
        const int cc = tid >> 3, rq = tid & 7;       // 64 cols x 8 row-chunks
        const unsigned short* sp = stage + cc * 136 + 16 * rq;
        bf16x8 v0 = *(const bf16x8*)sp;
        bf16x8 v1 = *(const bf16x8*)(sp + 8);
        unsigned short* gp = gm + (size_t)(64 * p + cc) * K_ + 16 * rq;
        *(bf16x8*)gp = v0;
        *(bf16x8*)(gp + 8) = v1;
    }
}

// ---------------- Phase 2: combine (64 blocks x 256 thr) -----------------
// v <- P_s * exp(sc + ln v - m) per segment, fp32, col-major P reads.
__global__ __launch_bounds__(256) void crf_combine_kernel(
    const unsigned short* __restrict__ mats,
    const float* __restrict__ scales,
    float* __restrict__ out)
{
    const int b = blockIdx.x, tid = threadIdx.x;
    const int lane = tid & 63;

    __shared__ float vS[K_], tS[K_], aS[K_], puS[2][K_];

    if (tid < K_) vS[tid] = (tid == 2) ? 1.0f : 0.0f;   // one-hot SOS
    float c = 0.0f;

    for (int sg = 0; sg < S_; ++sg) {
        __syncthreads();
        const float* sc = scales + ((size_t)b * S_ + sg) * K_;
        if (tid < K_) tS[tid] = sc[tid] + __logf(vS[tid]);
        __syncthreads();
        float m = fmaxf(tS[lane], tS[lane + 64]);
        m = fmaxf(m, __shfl_xor(m, 1));
        m = fmaxf(m, __shfl_xor(m, 2));
        m = fmaxf(m, __shfl_xor(m, 4));
        m = fmaxf(m, __shfl_xor(m, 8));
        m = fmaxf(m, __shfl_xor(m, 16));
        m = fmaxf(m, __shfl_xor(m, 32));
        if (tid < K_) aS[tid] = __expf(tS[tid] - m);
        __syncthreads();

        const unsigned short* P = mats + ((size_t)b * S_ + sg) * (K_ * K_);
        const int h = tid >> 7, i = tid & 127;
        float acc = 0.0f;
        #pragma unroll
        for (int j0 = 0; j0 < 64; ++j0) {
            const int j = 64 * h + j0;
            unsigned int uv = P[(size_t)j * K_ + i];          // coalesced
            float pv = __builtin_bit_cast(float, uv << 16);   // bf16 -> f32
            acc = fmaf(aS[j], pv, acc);
        }
        puS[h][i] = acc;
        __syncthreads();
        if (tid < K_) tS[tid] = puS[0][tid] + puS[1][tid];    // u_i
        __syncthreads();
        float Ssum = tS[lane] + tS[lane + 64];
        Ssum += __shfl_xor(Ssum, 1);
        Ssum += __shfl_xor(Ssum, 2);
        Ssum += __shfl_xor(Ssum, 4);
        Ssum += __shfl_xor(Ssum, 8);
        Ssum += __shfl_xor(Ssum, 16);
        Ssum += __shfl_xor(Ssum, 32);
        if (tid < K_) vS[tid] = tS[tid] * __builtin_amdgcn_rcpf(Ssum);
        c += m + __logf(Ssum);
    }
    if (tid == 0) out[b] = c;    // v normalized to sum 1 each segment
}

extern "C" void kernel_launch(void* const* d_in, const int* in_sizes, int n_in,
                              void* d_out, int out_size, void* d_ws, size_t ws_size,
                              hipStream_t stream) {
    const float* y     = (const float*)d_in[0];   // (B, T, K) fp32
    const float* mask  = (const float*)d_in[1];   // (B, T)    fp32 0/1
    const float* trans = (const float*)d_in[2];   // (K, K)    fp32
    float* out = (float*)d_out;                    // (B,)      fp32

    unsigned short* mats = (unsigned short*)d_ws;  // 512*128*128 bf16 = 16 MiB
    float* scales = (float*)((char*)d_ws + (size_t)B_ * S_ * K_ * K_ * 2);

    crf_seg_kernel<<<B_ * S_, 512, 0, stream>>>(y, mask, trans, mats, scales);
    crf_combine_kernel<<<B_, 256, 0, stream>>>(mats, scales, out);
}

// Round 13
// 167.398 us; speedup vs baseline: 1.3878x; 1.0009x over previous
//
#include <hip/hip_runtime.h>
#include <math.h>

#define B_ 64
#define T_ 256
#define K_ 128
#define S_ 8      // segments
#define SL_ 32    // segment length

typedef const __attribute__((address_space(1))) void* gas1_t;
typedef __attribute__((address_space(3))) void* las3_t;
typedef float f32x4 __attribute__((ext_vector_type(4)));
typedef int   i32x2 __attribute__((ext_vector_type(2)));
typedef int   i32x8 __attribute__((ext_vector_type(8)));
typedef short bf16x8 __attribute__((ext_vector_type(8)));

static __device__ __forceinline__ unsigned int bf16rne(float x) {
    unsigned int u = __builtin_bit_cast(unsigned int, x);
    return (u + 0x7FFFu + ((u >> 16) & 1u)) >> 16;
}
static __device__ __forceinline__ unsigned int pkbf16(float a, float b) {
    return bf16rne(a) | (bf16rne(b) << 16);
}
static __device__ __forceinline__ float bf8_to_f32(unsigned int byte) {
    // e5m2 == truncated fp16: byte<<8 are fp16 bits
    unsigned short h = (unsigned short)(byte << 8);
    return (float)__builtin_bit_cast(_Float16, h);
}
static __device__ __forceinline__ float hi_bf16(int d) {
    return __builtin_bit_cast(float, d & 0xFFFF0000);
}
static __device__ __forceinline__ float lo_bf16(int d) {
    return __builtin_bit_cast(float, d << 16);
}

// ---------------- Phase 1: segment products ------------------------------
// Block (b,s) = 512 thr = 8 waves; wave wv evolves columns [16wv,16wv+16) of
// P_s = prod_t diag(exp(y_t))*E as 16 independent register-closed matvec
// recurrences (sigma-permuted A rows; 8 x mfma_scale 16x16x128 per step).
// Per-lane-block power-2 bookkeeping with a LAGGED column reference:
//   Ng   = true log2 scale of lane's stored (normalized) block
//   Cref = max_g Ng from the PREVIOUS step (2 shfl_xor issued before the
//          MFMA phase, consumed next iteration -> off the critical path)
//   scaleB byte = 2^{Ng - Cref}; computed u = u_true * 2^{-Cref} stays ~2^30.
// R11 NaN'd because it reconstructed TRUE magnitudes in fp32 (overflow after
// ~18 steps -> n>127 -> invalid inv bit pattern). Working values now stay
// normalized; all exponent arithmetic is integer.
__global__ __launch_bounds__(512, 2) void crf_seg_kernel(
    const float* __restrict__ y,
    const float* __restrict__ mask,
    const float* __restrict__ trans,
    unsigned short* __restrict__ matsWS,   // (B*S, 128,128) col-major bf16
    float* __restrict__ scalesWS)          // (B*S, 128) per-column log scales
{
    const int bc  = blockIdx.x;            // b*S_ + s
    const int b   = bc >> 3;
    const int sg  = bc & 7;
    const int tid = threadIdx.x;
    const int wv  = tid >> 6;              // 0..7 : column tile
    const int lane = tid & 63;
    const int g   = lane >> 4;             // k-block / row-block selector
    const int ci  = lane & 15;             // column within tile (and A-row sel)

    __shared__ __align__(16) float bufA[4352];                 // 17.4KB raw y / export stage
    __shared__ __align__(16) unsigned short bufB16[SL_ * 136]; // 8.7KB bf16 exp(y)
    __shared__ int lenS[4];

    // ---- DMA y segment (16KB) ----
    const float* gy = y + ((size_t)b * T_ + sg * SL_) * K_;
    #pragma unroll
    for (int q = 0; q < 2; ++q) {
        const int seg = 2 * wv + q;
        __builtin_amdgcn_global_load_lds((gas1_t)(gy + seg * 256 + lane * 4),
                                         (las3_t)(bufA + seg * 256), 16, 0, 0);
    }

    // ---- sequence length (mask contiguous 1.0/0.0), waves 0..3 ----
    if (wv < 4) {
        float mval = mask[b * T_ + tid];
        unsigned long long bal = __ballot(mval != 0.0f);
        if (lane == 0) lenS[wv] = __popcll(bal);
    }

    // ---- A-frags: E=exp(trans) e4m3, rows sigma(rt,ci)=32(ci>>2)+4rt+(ci&3) ----
    i32x8 A[8];
    #pragma unroll
    for (int rt = 0; rt < 8; ++rt) {
        const int R = 32 * (ci >> 2) + 4 * rt + (ci & 3);
        const float* tp = trans + R * K_ + 32 * g;
        i32x8 a;
        #pragma unroll
        for (int dw = 0; dw < 8; ++dw) {
            f32x4 v4 = *(const f32x4*)(tp + 4 * dw);
            int d = 0;
            d = __builtin_amdgcn_cvt_pk_fp8_f32(__expf(v4.x), __expf(v4.y), d, false);
            d = __builtin_amdgcn_cvt_pk_fp8_f32(__expf(v4.z), __expf(v4.w), d, true);
            a[dw] = d;
        }
        A[rt] = a;
    }

    // ---- init B = identity column col0 = 16wv+ci (e5m2 1.0 = 0x3C) ----
    const int col0 = 16 * wv + ci;
    i32x8 Bv = (i32x8){0, 0, 0, 0, 0, 0, 0, 0};
    if (g == (wv >> 1)) {
        const int j = 16 * (wv & 1) + ci;        // k - 32g, in [0,32)
        Bv[j >> 2] = 0x3C << (8 * (j & 3));
    }

    asm volatile("s_waitcnt vmcnt(0)" ::: "memory");
    __syncthreads();

    // ---- pre-exp into bf16 LDS: [t][row], pitch 136 shorts ----
    {
        const int e0 = tid * 8;
        const int t0 = e0 >> 7, r0 = e0 & 127;
        f32x4 a = *(const f32x4*)(bufA + e0);
        f32x4 b2 = *(const f32x4*)(bufA + e0 + 4);
        uint4 u = make_uint4(pkbf16(__expf(a.x), __expf(a.y)),
                             pkbf16(__expf(a.z), __expf(a.w)),
                             pkbf16(__expf(b2.x), __expf(b2.y)),
                             pkbf16(__expf(b2.z), __expf(b2.w)));
        *(uint4*)(bufB16 + t0 * 136 + r0) = u;
    }
    __syncthreads();
    const int L = lenS[0] + lenS[1] + lenS[2] + lenS[3];   // in [128,256]
    int ns = L - sg * SL_;
    ns = ns < 0 ? 0 : (ns > SL_ ? SL_ : ns);

    int Ng   = 0;     // lane block's true log2 scale (stored block sum in [1,2))
    int Cref = 0;     // column-uniform lagged reference = max_g Ng (prev step)

    // ---- barrier-free scan: 8 MFMA/step; shuffles lag one full step ----
    for (int tt = 0; tt < ns; ++tt) {
        int sgm = Ng - Cref;
        sgm = sgm < -127 ? -127 : (sgm > 127 ? 127 : sgm);
        const int bscale = (sgm + 127) * 0x01010101;   // e8m0 byte, replicated

        // lagged column max for NEXT iteration (resolves during MFMA phase)
        int m1 = max(Ng, __shfl_xor(Ng, 16));
        const int Cnext = max(m1, __shfl_xor(m1, 32));

        const unsigned short* eyp = bufB16 + tt * 136 + 32 * g;
        f32x4 wws[8];
        f32x4 sv = {0.f, 0.f, 0.f, 0.f};
        #pragma unroll
        for (int rt = 0; rt < 8; ++rt) {
            f32x4 u = __builtin_amdgcn_mfma_scale_f32_16x16x128_f8f6f4(
                A[rt], Bv, (f32x4){0.f, 0.f, 0.f, 0.f},
                0 /*A fmt e4m3*/, 1 /*B fmt e5m2*/,
                0, 0x7F7F7F7F /*scaleA = 2^0*/, 0, bscale /*2^{Ng-Cref}*/);
            i32x2 eh = *(const i32x2*)(eyp + 4 * rt);      // rows 32g+4rt..+3
            f32x4 e4 = {lo_bf16(eh[0]), hi_bf16(eh[0]), lo_bf16(eh[1]), hi_bf16(eh[1])};
            f32x4 ww = u * e4;          // = true w * 2^{-Cref}: bounded ~2^30
            wws[rt] = ww;
            sv += ww;
        }
        // in-lane block sum -> power-2 exponent (all values >= 0)
        float Sb = (sv.x + sv.y) + (sv.z + sv.w);
        int n = ((__builtin_bit_cast(int, Sb) >> 23) & 255) - 127;  // floor log2
        n = n < -127 ? -127 : (n > 126 ? 126 : n);
        Ng = n + Cref;                  // new true exponent of the stored block
        const float inv = __builtin_bit_cast(float, (127 - n) << 23);  // 2^{-n}
        #pragma unroll
        for (int rt = 0; rt < 8; ++rt) {                   // Bv dead -> overwrite
            f32x4 w2 = wws[rt] * inv;                      // block sum in [1,2)
            int d = 0;
            d = __builtin_amdgcn_cvt_pk_bf8_f32(w2.x, w2.y, d, false);
            d = __builtin_amdgcn_cvt_pk_bf8_f32(w2.z, w2.w, d, true);
            Bv[rt] = d;
        }
        Cref = Cnext;
    }

    // ---- per-column scale unification (once per segment) ----
    int nc = Ng;
    nc = max(nc, __shfl_xor(nc, 16));
    nc = max(nc, __shfl_xor(nc, 32));
    if (g == 0) scalesWS[bc * K_ + col0] = (float)nc * 0.69314718056f;
    const int nd = Ng - nc;    // <= 0

    // ---- export P (decode Bv * 2^{nd}) col-major bf16, 2 passes ----
    unsigned short* stage = (unsigned short*)bufA;   // 64 cols x 136 pitch
    unsigned short* gm = matsWS + (size_t)bc * (K_ * K_);
    #pragma unroll
    for (int p = 0; p < 2; ++p) {
        __syncthreads();
        if ((wv >> 2) == p) {
            const int cl = 16 * (wv & 3) + ci;       // local column
            #pragma unroll
            for (int rt = 0; rt < 8; ++rt) {
                const unsigned int dwv = (unsigned int)Bv[rt];
                float f0 = ldexpf(bf8_to_f32(dwv & 255u), nd);
                float f1 = ldexpf(bf8_to_f32((dwv >> 8) & 255u), nd);
                float f2 = ldexpf(bf8_to_f32((dwv >> 16) & 255u), nd);
                float f3 = ldexpf(bf8_to_f32((dwv >> 24) & 255u), nd);
                uint2 d = make_uint2(pkbf16(f0, f1), pkbf16(f2, f3));
                *(uint2*)&stage[cl * 136 + 32 * g + 4 * rt] = d;   // rows 32g+4rt..+3
            }
        }
        __syncthreads();
        const int cc = tid >> 3, rq = tid & 7;       // 64 cols x 8 row-chunks
        const unsigned short* sp = stage + cc * 136 + 16 * rq;
        bf16x8 v0 = *(const bf16x8*)sp;
        bf16x8 v1 = *(const bf16x8*)(sp + 8);
        unsigned short* gp = gm + (size_t)(64 * p + cc) * K_ + 16 * rq;
        *(bf16x8*)gp = v0;
        *(bf16x8*)(gp + 8) = v1;
    }
}

// ---------------- Phase 2: combine (64 blocks x 256 thr) -----------------
// v <- P_s * exp(sc + ln v - m) per segment, fp32, col-major P reads.
__global__ __launch_bounds__(256) void crf_combine_kernel(
    const unsigned short* __restrict__ mats,
    const float* __restrict__ scales,
    float* __restrict__ out)
{
    const int b = blockIdx.x, tid = threadIdx.x;
    const int lane = tid & 63;

    __shared__ float vS[K_], tS[K_], aS[K_], puS[2][K_];

    if (tid < K_) vS[tid] = (tid == 2) ? 1.0f : 0.0f;   // one-hot SOS
    float c = 0.0f;

    for (int sg = 0; sg < S_; ++sg) {
        __syncthreads();
        const float* sc = scales + ((size_t)b * S_ + sg) * K_;
        if (tid < K_) tS[tid] = sc[tid] + __logf(vS[tid]);
        __syncthreads();
        float m = fmaxf(tS[lane], tS[lane + 64]);
        m = fmaxf(m, __shfl_xor(m, 1));
        m = fmaxf(m, __shfl_xor(m, 2));
        m = fmaxf(m, __shfl_xor(m, 4));
        m = fmaxf(m, __shfl_xor(m, 8));
        m = fmaxf(m, __shfl_xor(m, 16));
        m = fmaxf(m, __shfl_xor(m, 32));
        if (tid < K_) aS[tid] = __expf(tS[tid] - m);
        __syncthreads();

        const unsigned short* P = mats + ((size_t)b * S_ + sg) * (K_ * K_);
        const int h = tid >> 7, i = tid & 127;
        float acc = 0.0f;
        #pragma unroll
        for (int j0 = 0; j0 < 64; ++j0) {
            const int j = 64 * h + j0;
            unsigned int uv = P[(size_t)j * K_ + i];          // coalesced
            float pv = __builtin_bit_cast(float, uv << 16);   // bf16 -> f32
            acc = fmaf(aS[j], pv, acc);
        }
        puS[h][i] = acc;
        __syncthreads();
        if (tid < K_) tS[tid] = puS[0][tid] + puS[1][tid];    // u_i
        __syncthreads();
        float Ssum = tS[lane] + tS[lane + 64];
        Ssum += __shfl_xor(Ssum, 1);
        Ssum += __shfl_xor(Ssum, 2);
        Ssum += __shfl_xor(Ssum, 4);
        Ssum += __shfl_xor(Ssum, 8);
        Ssum += __shfl_xor(Ssum, 16);
        Ssum += __shfl_xor(Ssum, 32);
        if (tid < K_) vS[tid] = tS[tid] * __builtin_amdgcn_rcpf(Ssum);
        c += m + __logf(Ssum);
    }
    if (tid == 0) out[b] = c;    // v normalized to sum 1 each segment
}

extern "C" void kernel_launch(void* const* d_in, const int* in_sizes, int n_in,
                              void* d_out, int out_size, void* d_ws, size_t ws_size,
                              hipStream_t stream) {
    const float* y     = (const float*)d_in[0];   // (B, T, K) fp32
    const float* mask  = (const float*)d_in[1];   // (B, T)    fp32 0/1
    const float* trans = (const float*)d_in[2];   // (K, K)    fp32
    float* out = (float*)d_out;                    // (B,)      fp32

    unsigned short* mats = (unsigned short*)d_ws;  // 512*128*128 bf16 = 16 MiB
    float* scales = (float*)((char*)d_ws + (size_t)B_ * S_ * K_ * K_ * 2);

    crf_seg_kernel<<<B_ * S_, 512, 0, stream>>>(y, mask, trans, mats, scales);
    crf_combine_kernel<<<B_, 256, 0, stream>>>(mats, scales, out);
}